// Round 1
// baseline (423.138 us; speedup 1.0000x reference)
//
#include <hip/hip_runtime.h>
#include <math.h>

namespace {

constexpr int Bn    = 4;
constexpr int Hn    = 128;
constexpr int MODES = 256;
constexpr int NCn   = 65536;
constexpr int TN    = 64;    // tail n-tile per block: 32 KiB LDS -> 4 blocks/CU

typedef float nt_f2 __attribute__((ext_vector_type(2)));
typedef float nt_f4 __attribute__((ext_vector_type(4)));

__device__ __forceinline__ float gelu_f(float v) {
    return 0.5f * v * (1.0f + erff(v * 0.70710678118654752440f));
}

// ---- spectral: yr[b,k,m] = sum_h x[b,h,m]*w_real[h,k,m] + bias[k,m] --------
// block = (k, b), thread = m. w reads are contiguous along m (coalesced).
// b==0 blocks also emit one column of lwT (fused transpose; k_tail launches
// later on the same stream, so ordering is guaranteed).
__global__ __launch_bounds__(256) void k_spectral(
        const float* __restrict__ x, const float* __restrict__ w_real,
        const float* __restrict__ w_imag, const float* __restrict__ bias,
        const float* __restrict__ lin_w,
        float* __restrict__ yr, float* __restrict__ yi,
        float* __restrict__ lwT) {
    const int m = threadIdx.x;   // 0..255
    const int k = blockIdx.x;    // 0..127
    const int b = blockIdx.y;    // 0..3
    if (b == 0 && m < Hn) lwT[m * Hn + k] = lin_w[k * Hn + m];
    float ar = 0.f, ai = 0.f;
    const float* xp = x + b * Hn * NCn + m;          // stride NCn over h
    const float* wr = w_real + k * MODES + m;        // stride Hn*MODES over h
    const float* wi = w_imag + k * MODES + m;
    #pragma unroll 8
    for (int h = 0; h < Hn; ++h) {
        float xv = xp[h * NCn];
        ar = fmaf(xv, wr[h * Hn * MODES], ar);
        ai = fmaf(xv, wi[h * Hn * MODES], ai);
    }
    ar += bias[k * NCn + m];     // fold bias (real path only, m < MODES)
    int o = (b * Hn + k) * MODES + m;
    yr[o] = ar;
    yi[o] = ai;
}

// ---- head (n < MODES): z[b,k,m] = gelu(sum_h y[b,h,m]*lin_w[k,h] (+lin_b)) -
__global__ __launch_bounds__(256) void k_head(
        const float* __restrict__ yr, const float* __restrict__ yi,
        const float* __restrict__ lin_w, const float* __restrict__ lin_b,
        float* __restrict__ out) {
    const int m = threadIdx.x;
    const int k = blockIdx.x;
    const int b = blockIdx.y;
    float ar = 0.f, ai = 0.f;
    const float* yrp = yr + b * Hn * MODES + m;
    const float* yip = yi + b * Hn * MODES + m;
    const float* lw  = lin_w + k * Hn;               // uniform -> scalar loads
    #pragma unroll 8
    for (int h = 0; h < Hn; ++h) {
        float w = lw[h];
        ar = fmaf(w, yrp[h * MODES], ar);
        ai = fmaf(w, yip[h * MODES], ai);
    }
    ar += lin_b[k];
    nt_f2 o = {gelu_f(ar), gelu_f(ai)};
    __builtin_nontemporal_store(o,
        (nt_f2*)out + ((size_t)(b * Hn + k) * NCn + m));
}

// ---- tail (n >= MODES): t[k,n] = gelu(lin_w@bias[:,n] + lin_b[k]) ----------
// written to all 4 batches (real), imag = 0. Store-bound.
// TN=64 -> 32 KiB LDS -> 4 blocks/CU (was 2 at TN=128) for store-latency
// hiding. Lane mapping: lane tn (0..15), acc pair p (0..1) owns modes
// 32p+2tn+{0,1}; each float4 store is CONTIGUOUS across the 16 tn lanes
// (256 B segment). LDS reads: 16 lanes x float2 cover all 32 banks once,
// tk-groups are same-address broadcast -> conflict-free.
__global__ __launch_bounds__(256, 4) void k_tail(
        const float* __restrict__ bias, const float* __restrict__ lwT,
        const float* __restrict__ lin_b, float* __restrict__ out) {
    __shared__ float bs[Hn][TN];                     // 32 KiB
    const int n0 = MODES + blockIdx.x * TN;

    // stage bias[:, n0:n0+TN] into LDS, float4 coalesced (2048 float4)
    for (int i = threadIdx.x; i < Hn * (TN / 4); i += 256) {
        int h = i >> 4;              // TN/4 = 16 float4 per row
        int j = (i & 15) << 2;
        *(float4*)&bs[h][j] = *(const float4*)&bias[h * NCn + n0 + j];
    }
    __syncthreads();

    const int tn = threadIdx.x & 15;   // 16 n-groups
    const int tk = threadIdx.x >> 4;   // 16 k-groups of 8
    float acc[8][4];                   // [a = k-sub][c = 2p+q]
    #pragma unroll
    for (int a = 0; a < 8; ++a)
        #pragma unroll
        for (int c = 0; c < 4; ++c) acc[a][c] = 0.f;

    const float* lwp = lwT + tk * 8;   // lwT[h*H + k]
    #pragma unroll 2
    for (int h = 0; h < Hn; ++h) {
        float bv[4];
        #pragma unroll
        for (int p = 0; p < 2; ++p) {
            float2 v = *(const float2*)&bs[h][32 * p + 2 * tn];
            bv[2 * p]     = v.x;
            bv[2 * p + 1] = v.y;
        }
        float4 w0 = *(const float4*)&lwp[h * Hn];
        float4 w1 = *(const float4*)&lwp[h * Hn + 4];
        float wv[8] = {w0.x, w0.y, w0.z, w0.w, w1.x, w1.y, w1.z, w1.w};
        #pragma unroll
        for (int a = 0; a < 8; ++a)
            #pragma unroll
            for (int c = 0; c < 4; ++c)
                acc[a][c] = fmaf(wv[a], bv[c], acc[a][c]);
    }

    // epilogue: gelu once, broadcast to 4 batches. Store p covers modes
    // n0+32p+2tn+{0,1} as {real,0,real,0} -> contiguous 256 B per tk group.
    #pragma unroll
    for (int a = 0; a < 8; ++a) {
        int k = tk * 8 + a;
        float lb = lin_b[k];
        float t[4];
        #pragma unroll
        for (int c = 0; c < 4; ++c) t[c] = gelu_f(acc[a][c] + lb);
        #pragma unroll
        for (int b = 0; b < Bn; ++b) {
            size_t rowbase = (size_t)(b * Hn + k) * NCn;  // float2 units
            #pragma unroll
            for (int p = 0; p < 2; ++p) {
                nt_f4 pk = {t[2 * p], 0.f, t[2 * p + 1], 0.f};
                __builtin_nontemporal_store(pk,
                    (nt_f4*)out + ((rowbase + n0 + 32 * p + 2 * tn) >> 1));
            }
        }
    }
}

}  // namespace

extern "C" void kernel_launch(void* const* d_in, const int* in_sizes, int n_in,
                              void* d_out, int out_size, void* d_ws, size_t ws_size,
                              hipStream_t stream) {
    const float* x      = (const float*)d_in[0];
    const float* w_real = (const float*)d_in[1];
    const float* w_imag = (const float*)d_in[2];
    const float* bias   = (const float*)d_in[3];
    const float* lin_w  = (const float*)d_in[4];
    const float* lin_b  = (const float*)d_in[5];
    float* out = (float*)d_out;

    float* yr  = (float*)d_ws;                 // B*H*MODES fp32 = 512 KiB
    float* yi  = yr + Bn * Hn * MODES;         // 512 KiB
    float* lwT = yi + Bn * Hn * MODES;         // 64 KiB

    hipLaunchKernelGGL(k_spectral, dim3(Hn, Bn), dim3(MODES), 0, stream,
                       x, w_real, w_imag, bias, lin_w, yr, yi, lwT);
    hipLaunchKernelGGL(k_head, dim3(Hn, Bn), dim3(MODES), 0, stream,
                       yr, yi, lin_w, lin_b, out);
    hipLaunchKernelGGL(k_tail, dim3((NCn - MODES) / TN), dim3(256), 0, stream,
                       bias, lwT, lin_b, out);
}

// Round 2
// 415.523 us; speedup vs baseline: 1.0183x; 1.0183x over previous
//
#include <hip/hip_runtime.h>
#include <math.h>

namespace {

constexpr int Bn    = 4;
constexpr int Hn    = 128;
constexpr int MODES = 256;
constexpr int NCn   = 65536;
constexpr int TN    = 64;          // tail n-tile per block: 32 KiB LDS
constexpr int ROWF  = 2 * NCn;     // floats per (b,k) row of out = 131072
constexpr int HEADF = 2 * MODES;   // head region floats per row = 512
constexpr int YSZ   = Bn * Hn * MODES;  // 131072 floats per yr/yi plane

typedef float nt_f2 __attribute__((ext_vector_type(2)));
typedef float nt_f4 __attribute__((ext_vector_type(4)));
typedef float f4v   __attribute__((ext_vector_type(4)));

__device__ __forceinline__ float gelu_f(float v) {
    return 0.5f * v * (1.0f + erff(v * 0.70710678118654752440f));
}

// Scratch-in-output: float index s (0 .. 4*65536) maps into the TAIL region
// (n >= MODES) of out rows 0..3. k_tail rewrites the whole tail afterwards,
// so the scratch is transient. Runs of <=256 floats with 256-aligned base
// never straddle a 65536-chunk, so coalescing is preserved.
__device__ __forceinline__ float* scr(float* out, int s) {
    return out + (size_t)(s >> 16) * ROWF + HEADF + (s & 65535);
}

// ---- spectral: yr[b,k,m] = sum_h x[b,h,m]*w_real[h,k,m] + bias[k,m] --------
// block = (k, b), thread = m. w reads contiguous along m (coalesced).
// yr/yi go to scratch inside out (no workspace).
__global__ __launch_bounds__(256) void k_spectral(
        const float* __restrict__ x, const float* __restrict__ w_real,
        const float* __restrict__ w_imag, const float* __restrict__ bias,
        float* __restrict__ out) {
    const int m = threadIdx.x;   // 0..255
    const int k = blockIdx.x;    // 0..127
    const int b = blockIdx.y;    // 0..3
    float ar = 0.f, ai = 0.f;
    const float* xp = x + b * Hn * NCn + m;          // stride NCn over h
    const float* wr = w_real + k * MODES + m;        // stride Hn*MODES over h
    const float* wi = w_imag + k * MODES + m;
    #pragma unroll 8
    for (int h = 0; h < Hn; ++h) {
        float xv = xp[h * NCn];
        ar = fmaf(xv, wr[h * Hn * MODES], ar);
        ai = fmaf(xv, wi[h * Hn * MODES], ai);
    }
    ar += bias[k * NCn + m];     // fold bias (real path only, m < MODES)
    int o = (b * Hn + k) * MODES + m;
    *scr(out, o)       = ar;     // yr plane
    *scr(out, o + YSZ) = ai;     // yi plane
}

// ---- head (n < MODES): z[b,k,m] = gelu(sum_h y[b,h,m]*lin_w[k,h] (+lin_b)) -
// Reads yr/yi from the out-tail scratch; writes head region (disjoint).
__global__ __launch_bounds__(256) void k_head(
        const float* __restrict__ lin_w, const float* __restrict__ lin_b,
        float* __restrict__ out) {
    const int m = threadIdx.x;
    const int k = blockIdx.x;
    const int b = blockIdx.y;
    float ar = 0.f, ai = 0.f;
    // per-block scratch base: s = (b*Hn + h)*MODES + m stays in one chunk
    // for all h in 0..127, so plain stride-MODES pointers are valid.
    const float* yrp = scr(out, (b * Hn) * MODES + m);
    const float* yip = yrp + 2 * (size_t)ROWF;       // yi plane = +2 chunks
    const float* lw  = lin_w + k * Hn;               // uniform -> scalar loads
    #pragma unroll 8
    for (int h = 0; h < Hn; ++h) {
        float w = lw[h];
        ar = fmaf(w, yrp[h * MODES], ar);
        ai = fmaf(w, yip[h * MODES], ai);
    }
    ar += lin_b[k];
    nt_f2 o = {gelu_f(ar), gelu_f(ai)};
    __builtin_nontemporal_store(o,
        (nt_f2*)out + ((size_t)(b * Hn + k) * NCn + m));
}

// ---- tail (n >= MODES): t[k,n] = gelu(lin_w@bias[:,n] + lin_b[k]) ----------
// Written to all 4 batches (real), imag = 0. Store-bound.
// lin_w read DIRECTLY (row-major, float4 every 4 h, broadcast across the 16
// tn lanes; 64 KiB -> L1/L2 resident). No lwT, no workspace.
__global__ __launch_bounds__(256, 4) void k_tail(
        const float* __restrict__ bias, const float* __restrict__ lin_w,
        const float* __restrict__ lin_b, float* __restrict__ out) {
    __shared__ float bs[Hn][TN];                     // 32 KiB
    const int n0 = MODES + blockIdx.x * TN;

    // stage bias[:, n0:n0+TN] into LDS, float4 coalesced
    for (int i = threadIdx.x; i < Hn * (TN / 4); i += 256) {
        int h = i >> 4;              // TN/4 = 16 float4 per row
        int j = (i & 15) << 2;
        *(float4*)&bs[h][j] = *(const float4*)&bias[h * NCn + n0 + j];
    }
    __syncthreads();

    const int tn = threadIdx.x & 15;   // 16 n-groups
    const int tk = threadIdx.x >> 4;   // 16 k-groups of 8
    float acc[8][4];                   // [a = k-sub][c = 2p+q]
    #pragma unroll
    for (int a = 0; a < 8; ++a)
        #pragma unroll
        for (int c = 0; c < 4; ++c) acc[a][c] = 0.f;

    for (int h0 = 0; h0 < Hn; h0 += 4) {
        f4v wq[8];
        #pragma unroll
        for (int a = 0; a < 8; ++a)
            wq[a] = *(const f4v*)&lin_w[(tk * 8 + a) * Hn + h0];
        #pragma unroll
        for (int hh = 0; hh < 4; ++hh) {
            float bv[4];
            #pragma unroll
            for (int p = 0; p < 2; ++p) {
                float2 v = *(const float2*)&bs[h0 + hh][32 * p + 2 * tn];
                bv[2 * p]     = v.x;
                bv[2 * p + 1] = v.y;
            }
            #pragma unroll
            for (int a = 0; a < 8; ++a)
                #pragma unroll
                for (int c = 0; c < 4; ++c)
                    acc[a][c] = fmaf(wq[a][hh], bv[c], acc[a][c]);
        }
    }

    // epilogue: gelu once, broadcast to 4 batches. Store p covers modes
    // n0+32p+2tn+{0,1} as {real,0,real,0} -> contiguous 256 B per tk group.
    #pragma unroll
    for (int a = 0; a < 8; ++a) {
        int k = tk * 8 + a;
        float lb = lin_b[k];
        float t[4];
        #pragma unroll
        for (int c = 0; c < 4; ++c) t[c] = gelu_f(acc[a][c] + lb);
        #pragma unroll
        for (int b = 0; b < Bn; ++b) {
            size_t rowbase = (size_t)(b * Hn + k) * NCn;  // float2 units
            #pragma unroll
            for (int p = 0; p < 2; ++p) {
                nt_f4 pk = {t[2 * p], 0.f, t[2 * p + 1], 0.f};
                __builtin_nontemporal_store(pk,
                    (nt_f4*)out + ((rowbase + n0 + 32 * p + 2 * tn) >> 1));
            }
        }
    }
}

}  // namespace

extern "C" void kernel_launch(void* const* d_in, const int* in_sizes, int n_in,
                              void* d_out, int out_size, void* d_ws, size_t ws_size,
                              hipStream_t stream) {
    const float* x      = (const float*)d_in[0];
    const float* w_real = (const float*)d_in[1];
    const float* w_imag = (const float*)d_in[2];
    const float* bias   = (const float*)d_in[3];
    const float* lin_w  = (const float*)d_in[4];
    const float* lin_b  = (const float*)d_in[5];
    float* out = (float*)d_out;
    (void)d_ws; (void)ws_size;   // workspace intentionally unused

    hipLaunchKernelGGL(k_spectral, dim3(Hn, Bn), dim3(MODES), 0, stream,
                       x, w_real, w_imag, bias, out);
    hipLaunchKernelGGL(k_head, dim3(Hn, Bn), dim3(MODES), 0, stream,
                       lin_w, lin_b, out);
    hipLaunchKernelGGL(k_tail, dim3((NCn - MODES) / TN), dim3(256), 0, stream,
                       bias, lin_w, lin_b, out);
}